// Round 1
// baseline (667.047 us; speedup 1.0000x reference)
//
#include <hip/hip_runtime.h>
#include <hip/hip_bf16.h>
#include <cstdint>
#include <cstddef>

#define B_ 2
#define N_ 384
#define D_ 128
#define NN (N_*N_)                  // 147456
#define BN (B_*N_)                  // 768
#define EDGE_ELEMS (B_*NN*D_)       // 37748736
#define NODE_ELEMS (BN*D_)          // 98304

typedef short bh8 __attribute__((ext_vector_type(8)));
typedef float f32x4 __attribute__((ext_vector_type(4)));

__device__ __forceinline__ f32x4 mfma_bf16(bh8 a, bh8 b, f32x4 c){
  return __builtin_amdgcn_mfma_f32_16x16x32_bf16(a, b, c, 0, 0, 0);
}
__device__ __forceinline__ unsigned short f2bf(float f){
  unsigned u = __float_as_uint(f);
  return (unsigned short)((u + 0x7fffu + ((u >> 16) & 1u)) >> 16);
}
__device__ __forceinline__ unsigned f2bf_pk(float a, float b){   // packed cvt: lo=a, hi=b
  __hip_bfloat162 h = __float22bfloat162_rn(make_float2(a, b));
  return *(unsigned*)&h;
}
__device__ __forceinline__ float bf2f(unsigned short h){
  return __uint_as_float(((unsigned)h) << 16);
}
__device__ __forceinline__ float geluf(float x){        // exact (node path)
  return 0.5f * x * (1.0f + erff(x * 0.70710678118654752f));
}
__device__ __forceinline__ float gelu_fast(float x){    // tanh approx via hw exp
  float x2 = x * x;
  float t  = __fmaf_rn(0.044715f * x, x2, x);
  float e  = __expf(1.5957691216057308f * t);
  float r  = __builtin_amdgcn_rcpf(e + 1.0f);
  return x - x * r;
}
__device__ __forceinline__ f32x4 zero4(){ f32x4 z = {0.f,0.f,0.f,0.f}; return z; }

// ------- merged prep: y<5 weight bf16-transpose, y==5 node qkv GEMV -------
__global__ void kprep(const float* wqkv_e, const float* e0_we, const float* e0_w1,
                      const float* e1_w1, const float* e1_w2,
                      const float* node, const float* wqkv_n,
                      unsigned short* WqkvT, unsigned short* WeT, unsigned short* W1T,
                      unsigned short* E1W1T, unsigned short* E1W2T,
                      float* qkvn){
  int m = blockIdx.y;
  int tid = threadIdx.x;
  if (m < 5){
    const float* src; unsigned short* dst; int K, Nn;
    if (m == 0){ src = wqkv_e; dst = WqkvT; K = 128; Nn = 512; }
    else if (m == 1){ src = e0_we; dst = WeT;   K = 256; Nn = 128; }
    else if (m == 2){ src = e0_w1; dst = W1T;   K = 128; Nn = 128; }
    else if (m == 3){ src = e1_w1; dst = E1W1T; K = 128; Nn = 256; }
    else            { src = e1_w2; dst = E1W2T; K = 256; Nn = 128; }
    int idx = blockIdx.x * 384 + tid;
    if (idx < K * Nn){
      int n = idx / K, k = idx % K;
      dst[idx] = f2bf(src[k * Nn + n]);
    }
  } else {
    int row = blockIdx.x;
    __shared__ float sn[128];
    if (tid < 128) sn[tid] = node[row * 128 + tid];
    __syncthreads();
    float acc = 0.f;
    #pragma unroll 8
    for (int k = 0; k < 128; ++k) acc += sn[k] * wqkv_n[k * 384 + tid];
    qkvn[row * 384 + tid] = acc;
  }
}

// ---------------- fused: edge fp32 -> bf16 + meanJ (contiguous row pass) ----------------
__global__ void kprepA(const float* __restrict__ edge, unsigned short* __restrict__ E16,
                       float* __restrict__ meanJ){
  __shared__ float red[8][128];
  int bi = blockIdx.x; int tid = threadIdx.x;
  const float4* src = (const float4*)(edge + (size_t)bi * N_ * D_);
  uint2* gdst = (uint2*)E16 + (size_t)bi * (N_ * D_ / 4);
  float ps0 = 0.f, ps1 = 0.f, ps2 = 0.f, ps3 = 0.f;
  #pragma unroll 4
  for (int k = 0; k < 48; ++k){
    int idx = k * 256 + tid;
    float4 v = src[idx];
    uint2 o;
    o.x = f2bf_pk(v.x, v.y);
    o.y = f2bf_pk(v.z, v.w);
    gdst[idx] = o;
    ps0 += v.x; ps1 += v.y; ps2 += v.z; ps3 += v.w;
  }
  int g = tid >> 5, d0 = (tid & 31) * 4;
  red[g][d0] = ps0; red[g][d0 + 1] = ps1; red[g][d0 + 2] = ps2; red[g][d0 + 3] = ps3;
  __syncthreads();
  if (tid < 128){
    float s = 0.f;
    #pragma unroll
    for (int gg = 0; gg < 8; ++gg) s += red[gg][tid];
    meanJ[bi * 128 + tid] = s * (1.0f / N_);
  }
}

// ---- merged: y==0 attention (2 heads/wave, prefetch), y==1 meanI column pass ----
__global__ __launch_bounds__(256, 2) void kattnI(
    const unsigned short* __restrict__ E16, const unsigned short* __restrict__ WqkvT,
    const float* __restrict__ qkvn, float* __restrict__ attn,
    float* __restrict__ meanI){
  __shared__ float red[16][128];
  int tid = threadIdx.x;
  if (blockIdx.y == 1){
    // ---------------- meanI over i, vectorized 16B loads ----------------
    int bj = blockIdx.x; int b = bj / N_, j = bj % N_;
    int ig = tid >> 4, dsub = tid & 15;
    float acc[8];
    #pragma unroll
    for (int e = 0; e < 8; ++e) acc[e] = 0.f;
    #pragma unroll 4
    for (int i = ig; i < N_; i += 16){
      const unsigned short* p = E16 + ((size_t)(b * N_ + i) * N_ + j) * D_ + dsub * 8;
      uint4 u = *(const uint4*)p;
      acc[0] += bf2f((unsigned short)(u.x & 0xffff)); acc[1] += bf2f((unsigned short)(u.x >> 16));
      acc[2] += bf2f((unsigned short)(u.y & 0xffff)); acc[3] += bf2f((unsigned short)(u.y >> 16));
      acc[4] += bf2f((unsigned short)(u.z & 0xffff)); acc[5] += bf2f((unsigned short)(u.z >> 16));
      acc[6] += bf2f((unsigned short)(u.w & 0xffff)); acc[7] += bf2f((unsigned short)(u.w >> 16));
    }
    #pragma unroll
    for (int e = 0; e < 8; ++e) red[ig][dsub * 8 + e] = acc[e];
    __syncthreads();
    if (tid < 128){
      float s = 0.f;
      #pragma unroll
      for (int gg = 0; gg < 16; ++gg) s += red[gg][tid];
      meanI[bj * 128 + tid] = s * (1.0f / N_);
    }
    return;
  }
  // ---------------- attention ----------------
  int bi = blockIdx.x; int b = bi / N_;
  int w = tid >> 6, lane = tid & 63, quad = lane >> 4, c16 = lane & 15;
  const float scale = 0.08838834764831845f;   // 1/sqrt(128)
  const unsigned short* Abase = E16 + (size_t)bi * N_ * D_;

  bh8 bf[2][4][4];
  #pragma unroll
  for (int s = 0; s < 2; ++s){
    int h = w + s * 4;
    #pragma unroll
    for (int u = 0; u < 4; ++u)
      #pragma unroll
      for (int ks = 0; ks < 4; ++ks){
        int col = h * 64 + u * 16 + c16;
        bf[s][u][ks] = *(const bh8*)(WqkvT + col * 128 + ks * 32 + quad * 8);
      }
  }
  float qv[2];
  #pragma unroll
  for (int s = 0; s < 2; ++s) qv[s] = qkvn[bi * 384 + (w + s * 4) * 48 + c16];

  float m_run[2] = {-1e30f, -1e30f}, l_run[2] = {0.f, 0.f}, o[2] = {0.f, 0.f};
  bh8 af[4];
  #pragma unroll
  for (int ks = 0; ks < 4; ++ks)
    af[ks] = *(const bh8*)(Abase + (size_t)c16 * D_ + ks * 32 + quad * 8);

  for (int jt = 0; jt < 24; ++jt){
    int jn = (jt + 1 < 24) ? jt + 1 : 0;
    bh8 afn[4];
    #pragma unroll
    for (int ks = 0; ks < 4; ++ks)
      afn[ks] = *(const bh8*)(Abase + (size_t)(jn * 16 + c16) * D_ + ks * 32 + quad * 8);
    float knv[2][4], vnv[2][4];
    const float* kvb = qkvn + ((size_t)b * N_ + jt * 16 + quad * 4) * 384;
    #pragma unroll
    for (int s = 0; s < 2; ++s)
      #pragma unroll
      for (int r = 0; r < 4; ++r){
        knv[s][r] = kvb[r * 384 + (w + s * 4) * 48 + 16 + c16];
        vnv[s][r] = kvb[r * 384 + (w + s * 4) * 48 + 32 + c16];
      }
    f32x4 EQ[2], EK[2], EV[2], EM[2];
    #pragma unroll
    for (int s = 0; s < 2; ++s){ EQ[s] = zero4(); EK[s] = zero4(); EV[s] = zero4(); EM[s] = zero4(); }
    #pragma unroll
    for (int ks = 0; ks < 4; ++ks)
      #pragma unroll
      for (int s = 0; s < 2; ++s){
        EQ[s] = mfma_bf16(af[ks], bf[s][0][ks], EQ[s]);
        EK[s] = mfma_bf16(af[ks], bf[s][1][ks], EK[s]);
        EV[s] = mfma_bf16(af[ks], bf[s][2][ks], EV[s]);
        EM[s] = mfma_bf16(af[ks], bf[s][3][ks], EM[s]);
      }
    #pragma unroll
    for (int s = 0; s < 2; ++s){
      float dots[4], vv[4];
      #pragma unroll
      for (int r = 0; r < 4; ++r){
        float t1 = (qv[s] + EQ[s][r]) * (knv[s][r] + EK[s][r]);
        t1 += __shfl_xor(t1, 1); t1 += __shfl_xor(t1, 2);
        t1 += __shfl_xor(t1, 4); t1 += __shfl_xor(t1, 8);
        dots[r] = t1 * scale;
        vv[r] = vnv[s][r] * EM[s][r] + EV[s][r];
      }
      float tmax = fmaxf(fmaxf(dots[0], dots[1]), fmaxf(dots[2], dots[3]));
      tmax = fmaxf(tmax, __shfl_xor(tmax, 16));
      tmax = fmaxf(tmax, __shfl_xor(tmax, 32));
      float mnew = fmaxf(m_run[s], tmax);
      float al = __expf(m_run[s] - mnew);
      float p0 = __expf(dots[0] - mnew), p1 = __expf(dots[1] - mnew);
      float p2 = __expf(dots[2] - mnew), p3 = __expf(dots[3] - mnew);
      float lt = p0 + p1 + p2 + p3;
      lt += __shfl_xor(lt, 16); lt += __shfl_xor(lt, 32);
      l_run[s] = l_run[s] * al + lt;
      m_run[s] = mnew;
      o[s] = o[s] * al + p0 * vv[0] + p1 * vv[1] + p2 * vv[2] + p3 * vv[3];
    }
    #pragma unroll
    for (int ks = 0; ks < 4; ++ks) af[ks] = afn[ks];
  }
  #pragma unroll
  for (int s = 0; s < 2; ++s){
    float oo = o[s];
    oo += __shfl_xor(oo, 16); oo += __shfl_xor(oo, 32);
    oo /= l_run[s];
    if (quad == 0) attn[(size_t)bi * D_ + (w + s * 4) * 16 + c16] = oo;
  }
}

// -------- merged node path: lin0+LN0+MLP+LN1 then rowAdd/colAdd GEMVs --------
__global__ void knodeadd(const float* __restrict__ node, const float* __restrict__ attn,
                         const float* lin0_w, const float* lin0_b,
                         const float* g0, const float* bb0,
                         const float* w1, const float* w2, const float* b2,
                         const float* g1, const float* bb1,
                         const float* __restrict__ meanJ, const float* __restrict__ meanI,
                         const float* ws, const float* bs, const float* wt, const float* bt,
                         const float* wer, const float* wec, const float* be,
                         float* __restrict__ xOut,
                         float* __restrict__ rowAdd, float* __restrict__ colAdd){
  int row = blockIdx.x; int tid = threadIdx.x;
  __shared__ float sa[128], sx[128], sh[256], rb[8], sx2[128], smJ[128], smI[128];
  if (tid < 128){
    sa[tid] = attn[row * 128 + tid];
    smJ[tid] = meanJ[row * 128 + tid];
    smI[tid] = meanI[row * 128 + tid];
  }
  __syncthreads();
  float y = 0.f, x0 = 0.f;
  if (tid < 128){
    float acc = lin0_b[tid];
    #pragma unroll 8
    for (int k = 0; k < 128; ++k) acc += sa[k] * lin0_w[k * 128 + tid];
    y = acc + node[row * 128 + tid];
  }
  { float sv = (tid < 128) ? y : 0.f, sq = (tid < 128) ? y * y : 0.f;
    #pragma unroll
    for (int m2 = 32; m2 >= 1; m2 >>= 1){ sv += __shfl_xor(sv, m2); sq += __shfl_xor(sq, m2); }
    if ((tid & 63) == 0){ rb[tid >> 6] = sv; rb[4 + (tid >> 6)] = sq; } }
  __syncthreads();
  float mean = (rb[0] + rb[1] + rb[2] + rb[3]) * (1.f / 128.f);
  float var  = (rb[4] + rb[5] + rb[6] + rb[7]) * (1.f / 128.f) - mean * mean;
  float rstd = rsqrtf(var + 1e-5f);
  if (tid < 128){ x0 = (y - mean) * rstd * g0[tid] + bb0[tid]; sx[tid] = x0; }
  __syncthreads();
  { float acc = 0.f;
    #pragma unroll 8
    for (int k = 0; k < 128; ++k) acc += sx[k] * w1[k * 256 + tid];
    sh[tid] = geluf(acc); }
  __syncthreads();
  float y2 = 0.f;
  if (tid < 128){
    float acc = b2[tid];
    #pragma unroll 8
    for (int e = 0; e < 256; ++e) acc += sh[e] * w2[e * 128 + tid];
    y2 = acc + x0;
  }
  __syncthreads();
  { float sv = (tid < 128) ? y2 : 0.f, sq = (tid < 128) ? y2 * y2 : 0.f;
    #pragma unroll
    for (int m2 = 32; m2 >= 1; m2 >>= 1){ sv += __shfl_xor(sv, m2); sq += __shfl_xor(sq, m2); }
    if ((tid & 63) == 0){ rb[tid >> 6] = sv; rb[4 + (tid >> 6)] = sq; } }
  __syncthreads();
  mean = (rb[0] + rb[1] + rb[2] + rb[3]) * (1.f / 128.f);
  var  = (rb[4] + rb[5] + rb[6] + rb[7]) * (1.f / 128.f) - mean * mean;
  rstd = rsqrtf(var + 1e-5f);
  if (tid < 128){
    float xv = (y2 - mean) * rstd * g1[tid] + bb1[tid];
    xOut[row * 128 + tid] = xv;
    sx2[tid] = xv;
  }
  __syncthreads();
  // ---- addends: tid<128 -> rowAdd (ws, wer); tid>=128 -> colAdd (wt, wec) ----
  if (tid < 128){
    int d = tid;
    float s1 = bs[d], s3 = 0.f;
    #pragma unroll 8
    for (int k = 0; k < 128; ++k){
      s1 += sx2[k] * ws[k * 128 + d];
      s3 += smJ[k] * wer[k * 128 + d];
    }
    rowAdd[row * 128 + d] = s1 + s3 + be[d];
  } else {
    int d = tid - 128;
    float s2 = bt[d], s4 = 0.f;
    #pragma unroll 8
    for (int k = 0; k < 128; ++k){
      s2 += sx2[k] * wt[k * 128 + d];
      s4 += smI[k] * wec[k * 128 + d];
    }
    colAdd[row * 128 + d] = s2 + s4;
  }
}

// -- fused edge pipeline v5: 8-wave (512-thr) blocks, 64-row tile, 16 cols/wave.
//    LDS = sA 33792 + sT 17408 = 51200 B -> 3 blocks/CU = 24 waves/CU (was 12).
//    LN scratch (lrS/lrQ/stats) aliases the head of sT (dead at those points);
//    per-row (mean,rstd) computed once by a designated wave, broadcast as float2.
__global__ __launch_bounds__(512, 6) void kedge4(
    const unsigned short* __restrict__ E16, const unsigned short* __restrict__ WeT,
    const unsigned short* __restrict__ W1T, const unsigned short* __restrict__ E1W1T,
    const unsigned short* __restrict__ E1W2T,
    const float* __restrict__ rowAdd, const float* __restrict__ colAdd,
    const float* __restrict__ b1, const float* __restrict__ eg0, const float* __restrict__ eb0,
    const float* __restrict__ e1b2, const float* __restrict__ eg1, const float* __restrict__ eb1,
    float* __restrict__ eOut){
  __shared__ unsigned short sA[64][264];   // edge|edgeT; cols 0..127 become edge2 after LN0
  __shared__ unsigned short sT[64][136];   // 128-wide stage buffer; head doubles as LN scratch
  float*  lrS   = (float*)&sT[0][0];       // [8][72] padded: stride-72 keeps gather <=2-way
  float*  lrQ   = lrS + 8 * 72;
  float2* stats = (float2*)(lrQ + 8 * 72); // [64] per-row (mean, rstd)
  int tid = threadIdx.x;
  int w = tid >> 6, lane = tid & 63, quad = lane >> 4, c16 = lane & 15;
  int c = w * 16 + c16;                    // this wave's output column, 0..127
  int R0 = blockIdx.x * 64;
  int b = R0 / NN; int rem = R0 % NN; int i = rem / N_; int j0 = rem % N_;

  // ---- stage A = [edge(b,i,j0+m,:) | edge(b,j0+m,i,:)] bf16, 64x256 ----
  #pragma unroll
  for (int it = 0; it < 4; ++it){
    int cid = it * 512 + tid;
    int rrow = cid >> 5;
    int kc = (cid & 31) * 8;
    const unsigned short* sp;
    if (kc < 128) sp = E16 + ((size_t)(b * N_ + i) * N_ + (j0 + rrow)) * D_ + kc;
    else          sp = E16 + ((size_t)(b * N_ + j0 + rrow) * N_ + i) * D_ + (kc - 128);
    *(float4*)&sA[rrow][kc] = *(const float4*)sp;
  }
  // G1 weights overlap staging latency
  bh8 wb1[8];
  #pragma unroll
  for (int ks = 0; ks < 8; ++ks)
    wb1[ks] = *(const bh8*)(WeT + (size_t)c * 256 + ks * 32 + quad * 8);
  __syncthreads();                                         // B1: sA staged

  // ---- G1: A(64x256) @ WeT^T -> col c; +rowAdd+colAdd, gelu -> sT ----
  f32x4 acc1[4];
  #pragma unroll
  for (int ms = 0; ms < 4; ++ms) acc1[ms] = zero4();
  #pragma unroll
  for (int ks = 0; ks < 8; ++ks){
    bh8 af[4];
    #pragma unroll
    for (int ms = 0; ms < 4; ++ms)
      af[ms] = *(const bh8*)&sA[ms * 16 + c16][ks * 32 + quad * 8];
    #pragma unroll
    for (int ms = 0; ms < 4; ++ms)
      acc1[ms] = mfma_bf16(af[ms], wb1[ks], acc1[ms]);
  }
  // addends loaded late (short live range; L2-hot)
  float rAv = rowAdd[(b * N_ + i) * D_ + c];
  float ca[16];
  #pragma unroll
  for (int ms = 0; ms < 4; ++ms)
    #pragma unroll
    for (int r = 0; r < 4; ++r)
      ca[ms * 4 + r] = colAdd[(size_t)(b * N_ + j0 + ms * 16 + quad * 4 + r) * D_ + c];
  #pragma unroll
  for (int ms = 0; ms < 4; ++ms)
    #pragma unroll
    for (int r = 0; r < 4; ++r){
      int m = ms * 16 + quad * 4 + r;
      float v = gelu_fast(acc1[ms][r] + rAv + ca[ms * 4 + r]);
      sT[m][c] = f2bf(v);
    }
  __syncthreads();                                         // B2: sT(gelu1) ready

  // ---- G2: gelu1 @ W1T^T + b1 + edge(bf16, sA) ----
  bh8 wb2[4];
  #pragma unroll
  for (int ks = 0; ks < 4; ++ks)
    wb2[ks] = *(const bh8*)(W1T + (size_t)c * 128 + ks * 32 + quad * 8);
  f32x4 acc2[4];
  #pragma unroll
  for (int ms = 0; ms < 4; ++ms) acc2[ms] = zero4();
  #pragma unroll
  for (int ks = 0; ks < 4; ++ks){
    bh8 af[4];
    #pragma unroll
    for (int ms = 0; ms < 4; ++ms)
      af[ms] = *(const bh8*)&sT[ms * 16 + c16][ks * 32 + quad * 8];
    #pragma unroll
    for (int ms = 0; ms < 4; ++ms)
      acc2[ms] = mfma_bf16(af[ms], wb2[ks], acc2[ms]);
  }
  float b1v = b1[c], g0v = eg0[c], b0v = eb0[c];
  #pragma unroll
  for (int ms = 0; ms < 4; ++ms)
    #pragma unroll
    for (int r = 0; r < 4; ++r){
      int m = ms * 16 + quad * 4 + r;
      acc2[ms][r] = acc2[ms][r] + b1v + bf2f(sA[m][c]);
    }
  __syncthreads();                                         // B3a: all sT reads done (lr aliases sT)
  #pragma unroll
  for (int ms = 0; ms < 4; ++ms)
    #pragma unroll
    for (int r = 0; r < 4; ++r){
      int m = ms * 16 + quad * 4 + r;
      float s = acc2[ms][r], q = s * s;
      s += __shfl_xor(s, 1); s += __shfl_xor(s, 2); s += __shfl_xor(s, 4); s += __shfl_xor(s, 8);
      q += __shfl_xor(q, 1); q += __shfl_xor(q, 2); q += __shfl_xor(q, 4); q += __shfl_xor(q, 8);
      if (c16 == 0){ lrS[w * 72 + m] = s; lrQ[w * 72 + m] = q; }
    }
  __syncthreads();                                         // B3b: lr partials ready
  {                                                        // wave w -> stats for rows [8w, 8w+8)
    int ww = lane & 7, dd = lane >> 3, mrow = w * 8 + dd;
    float sp = lrS[ww * 72 + mrow], qp = lrQ[ww * 72 + mrow];
    sp += __shfl_xor(sp, 1); sp += __shfl_xor(sp, 2); sp += __shfl_xor(sp, 4);
    qp += __shfl_xor(qp, 1); qp += __shfl_xor(qp, 2); qp += __shfl_xor(qp, 4);
    float mean = sp * (1.f / 128.f);
    float var  = qp * (1.f / 128.f) - mean * mean;
    float rstd = rsqrtf(var + 1e-5f);
    if (ww == 0) stats[mrow] = make_float2(mean, rstd);
  }
  __syncthreads();                                         // B4a: stats ready
  // LN0 finalize -> edge2 bf16 into sA cols 0..127
  #pragma unroll
  for (int ms = 0; ms < 4; ++ms)
    #pragma unroll
    for (int r = 0; r < 4; ++r){
      int m = ms * 16 + quad * 4 + r;
      float2 st = stats[m];
      float e0 = (acc2[ms][r] - st.x) * st.y * g0v + b0v;
      sA[m][c] = f2bf(e0);
    }
  __syncthreads();                                         // B4b: edge2 ready

  // ---- G3/G4 two-phase over K=256 ----
  f32x4 acc4[4];
  #pragma unroll
  for (int ms = 0; ms < 4; ++ms) acc4[ms] = zero4();
  #pragma unroll
  for (int p = 0; p < 2; ++p){
    bh8 wb3[4];
    #pragma unroll
    for (int ks = 0; ks < 4; ++ks)
      wb3[ks] = *(const bh8*)(E1W1T + (size_t)(p * 128 + c) * 128 + ks * 32 + quad * 8);
    f32x4 acc3[4];
    #pragma unroll
    for (int ms = 0; ms < 4; ++ms) acc3[ms] = zero4();
    #pragma unroll
    for (int ks = 0; ks < 4; ++ks){
      bh8 af[4];
      #pragma unroll
      for (int ms = 0; ms < 4; ++ms)
        af[ms] = *(const bh8*)&sA[ms * 16 + c16][ks * 32 + quad * 8];
      #pragma unroll
      for (int ms = 0; ms < 4; ++ms)
        acc3[ms] = mfma_bf16(af[ms], wb3[ks], acc3[ms]);
    }
    #pragma unroll
    for (int ms = 0; ms < 4; ++ms)
      #pragma unroll
      for (int r = 0; r < 4; ++r){
        int m = ms * 16 + quad * 4 + r;
        sT[m][c] = f2bf(gelu_fast(acc3[ms][r]));
      }
    __syncthreads();                                       // B5/B7: sT(gelu3 phase p) ready
    bh8 wb4[4];
    #pragma unroll
    for (int k2 = 0; k2 < 4; ++k2)
      wb4[k2] = *(const bh8*)(E1W2T + (size_t)c * 256 + p * 128 + k2 * 32 + quad * 8);
    #pragma unroll
    for (int k2 = 0; k2 < 4; ++k2){
      bh8 af[4];
      #pragma unroll
      for (int ms = 0; ms < 4; ++ms)
        af[ms] = *(const bh8*)&sT[ms * 16 + c16][k2 * 32 + quad * 8];
      #pragma unroll
      for (int ms = 0; ms < 4; ++ms)
        acc4[ms] = mfma_bf16(af[ms], wb4[k2], acc4[ms]);
    }
    __syncthreads();                                       // B6/B8: sT reads done
  }

  // ---- G4 epilogue: + b2 + edge2(bf16, sA) -> LN1 -> store ----
  float b2v = e1b2[c], g1v = eg1[c], bb1v = eb1[c];
  #pragma unroll
  for (int ms = 0; ms < 4; ++ms)
    #pragma unroll
    for (int r = 0; r < 4; ++r){
      int m = ms * 16 + quad * 4 + r;
      acc4[ms][r] = acc4[ms][r] + b2v + bf2f(sA[m][c]);
    }
  #pragma unroll
  for (int ms = 0; ms < 4; ++ms)
    #pragma unroll
    for (int r = 0; r < 4; ++r){
      int m = ms * 16 + quad * 4 + r;
      float s = acc4[ms][r], q = s * s;
      s += __shfl_xor(s, 1); s += __shfl_xor(s, 2); s += __shfl_xor(s, 4); s += __shfl_xor(s, 8);
      q += __shfl_xor(q, 1); q += __shfl_xor(q, 2); q += __shfl_xor(q, 4); q += __shfl_xor(q, 8);
      if (c16 == 0){ lrS[w * 72 + m] = s; lrQ[w * 72 + m] = q; }
    }
  __syncthreads();                                         // B9: lr partials ready
  {
    int ww = lane & 7, dd = lane >> 3, mrow = w * 8 + dd;
    float sp = lrS[ww * 72 + mrow], qp = lrQ[ww * 72 + mrow];
    sp += __shfl_xor(sp, 1); sp += __shfl_xor(sp, 2); sp += __shfl_xor(sp, 4);
    qp += __shfl_xor(qp, 1); qp += __shfl_xor(qp, 2); qp += __shfl_xor(qp, 4);
    float mean = sp * (1.f / 128.f);
    float var  = qp * (1.f / 128.f) - mean * mean;
    float rstd = rsqrtf(var + 1e-5f);
    if (ww == 0) stats[mrow] = make_float2(mean, rstd);
  }
  __syncthreads();                                         // B10: stats ready
  float* outBase = eOut + ((size_t)(b * N_ + i) * N_ + j0) * D_;
  #pragma unroll
  for (int ms = 0; ms < 4; ++ms)
    #pragma unroll
    for (int r = 0; r < 4; ++r){
      int m = ms * 16 + quad * 4 + r;
      float2 st = stats[m];
      outBase[(size_t)m * D_ + c] = (acc4[ms][r] - st.x) * st.y * g1v + bb1v;
    }
}

extern "C" void kernel_launch(void* const* d_in, const int* in_sizes, int n_in,
                              void* d_out, int out_size, void* d_ws, size_t ws_size,
                              hipStream_t stream){
  const float* node   = (const float*)d_in[0];
  const float* edge   = (const float*)d_in[1];
  const float* wqkv_n = (const float*)d_in[3];
  const float* wqkv_e = (const float*)d_in[4];
  const float* lin0_w = (const float*)d_in[5];
  const float* lin0_b = (const float*)d_in[6];
  const float* ln0_g  = (const float*)d_in[7];
  const float* ln0_b  = (const float*)d_in[8];
  const float* ln1_g  = (const float*)d_in[9];
  const float* ln1_b  = (const float*)d_in[10];
  const float* nmlp_w1= (const float*)d_in[11];
  const float* nmlp_w2= (const float*)d_in[12];
  const float* nmlp_b2= (const float*)d_in[13];
  const float* e0_we  = (const float*)d_in[14];
  const float* e0_be  = (const float*)d_in[15];
  const float* e0_ws  = (const float*)d_in[16];
  const float* e0_bs  = (const float*)d_in[17];
  const float* e0_wt  = (const float*)d_in[18];
  const float* e0_bt  = (const float*)d_in[19];
  const float* e0_wer = (const float*)d_in[20];
  const float* e0_wec = (const float*)d_in[21];
  const float* e0_w1  = (const float*)d_in[22];
  const float* e0_b1  = (const float*)d_in[23];
  const float* e1_w1  = (const float*)d_in[24];
  const float* e1_w2  = (const float*)d_in[25];
  const float* e1_b2  = (const float*)d_in[26];
  const float* eln0_g = (const float*)d_in[27];
  const float* eln0_b = (const float*)d_in[28];
  const float* eln1_g = (const float*)d_in[29];
  const float* eln1_b = (const float*)d_in[30];

  unsigned short* E16   = (unsigned short*)d_ws;
  unsigned short* WqkvT = E16 + (size_t)EDGE_ELEMS;
  unsigned short* WeT   = WqkvT + 65536;
  unsigned short* W1T   = WeT + 32768;
  unsigned short* E1W1T = W1T + 16384;
  unsigned short* E1W2T = E1W1T + 32768;
  float* fbase  = (float*)(E1W2T + 32768);
  float* qkvn   = fbase;
  float* attn   = qkvn + (size_t)BN * 384;
  float* meanJ  = attn + NODE_ELEMS;
  float* meanI  = meanJ + NODE_ELEMS;
  float* rowAdd = meanI + NODE_ELEMS;
  float* colAdd = rowAdd + NODE_ELEMS;

  float* xOut = (float*)d_out;
  float* eOut = xOut + NODE_ELEMS;

  kprep<<<dim3(BN, 6), 384, 0, stream>>>(wqkv_e, e0_we, e0_w1, e1_w1, e1_w2,
                                         node, wqkv_n,
                                         WqkvT, WeT, W1T, E1W1T, E1W2T, qkvn);
  kprepA<<<BN, 256, 0, stream>>>(edge, E16, meanJ);
  kattnI<<<dim3(BN, 2), 256, 0, stream>>>(E16, WqkvT, qkvn, attn, meanI);
  knodeadd<<<BN, 256, 0, stream>>>(node, attn, lin0_w, lin0_b, ln0_g, ln0_b,
                                   nmlp_w1, nmlp_w2, nmlp_b2, ln1_g, ln1_b,
                                   meanJ, meanI, e0_ws, e0_bs, e0_wt, e0_bt,
                                   e0_wer, e0_wec, e0_be,
                                   xOut, rowAdd, colAdd);
  kedge4<<<NN * B_ / 64, 512, 0, stream>>>(E16, WeT, W1T, E1W1T, E1W2T,
                                           rowAdd, colAdd, e0_b1,
                                           eln0_g, eln0_b, e1_b2, eln1_g, eln1_b,
                                           eOut);
}

// Round 2
// 635.976 us; speedup vs baseline: 1.0489x; 1.0489x over previous
//
#include <hip/hip_runtime.h>
#include <hip/hip_bf16.h>
#include <cstdint>
#include <cstddef>

#define B_ 2
#define N_ 384
#define D_ 128
#define NN (N_*N_)                  // 147456
#define BN (B_*N_)                  // 768
#define EDGE_ELEMS (B_*NN*D_)       // 37748736
#define NODE_ELEMS (BN*D_)          // 98304

typedef short bh8 __attribute__((ext_vector_type(8)));
typedef float f32x4 __attribute__((ext_vector_type(4)));

__device__ __forceinline__ f32x4 mfma_bf16(bh8 a, bh8 b, f32x4 c){
  return __builtin_amdgcn_mfma_f32_16x16x32_bf16(a, b, c, 0, 0, 0);
}
__device__ __forceinline__ unsigned short f2bf(float f){
  unsigned u = __float_as_uint(f);
  return (unsigned short)((u + 0x7fffu + ((u >> 16) & 1u)) >> 16);
}
__device__ __forceinline__ unsigned f2bf_pk(float a, float b){   // packed cvt: lo=a, hi=b
  __hip_bfloat162 h = __float22bfloat162_rn(make_float2(a, b));
  return *(unsigned*)&h;
}
__device__ __forceinline__ float bf2f(unsigned short h){
  return __uint_as_float(((unsigned)h) << 16);
}
__device__ __forceinline__ float geluf(float x){        // exact (node path)
  return 0.5f * x * (1.0f + erff(x * 0.70710678118654752f));
}
__device__ __forceinline__ float gelu_fast(float x){    // tanh approx via hw exp
  float x2 = x * x;
  float t  = __fmaf_rn(0.044715f * x, x2, x);
  float e  = __expf(1.5957691216057308f * t);
  float r  = __builtin_amdgcn_rcpf(e + 1.0f);
  return x - x * r;
}
__device__ __forceinline__ f32x4 zero4(){ f32x4 z = {0.f,0.f,0.f,0.f}; return z; }

// ---- DPP reductions (VALU pipe; replaces ds_swizzle-based __shfl_xor) ----
// sum over the 16-lane DPP row (equivalent to shfl_xor 1,2,4,8)
__device__ __forceinline__ float red16_add(float x){
  x += __int_as_float(__builtin_amdgcn_update_dpp(0, __float_as_int(x), 0xB1, 0xF, 0xF, true));  // quad_perm [1,0,3,2]
  x += __int_as_float(__builtin_amdgcn_update_dpp(0, __float_as_int(x), 0x4E, 0xF, 0xF, true));  // quad_perm [2,3,0,1]
  x += __int_as_float(__builtin_amdgcn_update_dpp(0, __float_as_int(x), 0x141, 0xF, 0xF, true)); // row_half_mirror
  x += __int_as_float(__builtin_amdgcn_update_dpp(0, __float_as_int(x), 0x140, 0xF, 0xF, true)); // row_mirror
  return x;
}
// sum over aligned 4-lane groups
__device__ __forceinline__ float red4_add(float x){
  x += __int_as_float(__builtin_amdgcn_update_dpp(0, __float_as_int(x), 0xB1, 0xF, 0xF, true));
  x += __int_as_float(__builtin_amdgcn_update_dpp(0, __float_as_int(x), 0x4E, 0xF, 0xF, true));
  return x;
}
// XOR chunk swizzle: logical (row m, col c in shorts) -> physical col. 16B chunk ^= m&7.
__device__ __forceinline__ int swz(int m, int c){
  return ((((c >> 3) ^ (m & 7)) << 3) | (c & 7));
}

// ------- merged prep: y<5 weight bf16-transpose, y==5 node qkv GEMV -------
__global__ void kprep(const float* wqkv_e, const float* e0_we, const float* e0_w1,
                      const float* e1_w1, const float* e1_w2,
                      const float* node, const float* wqkv_n,
                      unsigned short* WqkvT, unsigned short* WeT, unsigned short* W1T,
                      unsigned short* E1W1T, unsigned short* E1W2T,
                      float* qkvn){
  int m = blockIdx.y;
  int tid = threadIdx.x;
  if (m < 5){
    const float* src; unsigned short* dst; int K, Nn;
    if (m == 0){ src = wqkv_e; dst = WqkvT; K = 128; Nn = 512; }
    else if (m == 1){ src = e0_we; dst = WeT;   K = 256; Nn = 128; }
    else if (m == 2){ src = e0_w1; dst = W1T;   K = 128; Nn = 128; }
    else if (m == 3){ src = e1_w1; dst = E1W1T; K = 128; Nn = 256; }
    else            { src = e1_w2; dst = E1W2T; K = 256; Nn = 128; }
    int idx = blockIdx.x * 384 + tid;
    if (idx < K * Nn){
      int n = idx / K, k = idx % K;
      dst[idx] = f2bf(src[k * Nn + n]);
    }
  } else {
    int row = blockIdx.x;
    __shared__ float sn[128];
    if (tid < 128) sn[tid] = node[row * 128 + tid];
    __syncthreads();
    float acc = 0.f;
    #pragma unroll 8
    for (int k = 0; k < 128; ++k) acc += sn[k] * wqkv_n[k * 384 + tid];
    qkvn[row * 384 + tid] = acc;
  }
}

// ---------------- fused: edge fp32 -> bf16 + meanJ (contiguous row pass) ----------------
__global__ void kprepA(const float* __restrict__ edge, unsigned short* __restrict__ E16,
                       float* __restrict__ meanJ){
  __shared__ float red[8][128];
  int bi = blockIdx.x; int tid = threadIdx.x;
  const float4* src = (const float4*)(edge + (size_t)bi * N_ * D_);
  uint2* gdst = (uint2*)E16 + (size_t)bi * (N_ * D_ / 4);
  float ps0 = 0.f, ps1 = 0.f, ps2 = 0.f, ps3 = 0.f;
  #pragma unroll 4
  for (int k = 0; k < 48; ++k){
    int idx = k * 256 + tid;
    float4 v = src[idx];
    uint2 o;
    o.x = f2bf_pk(v.x, v.y);
    o.y = f2bf_pk(v.z, v.w);
    gdst[idx] = o;
    ps0 += v.x; ps1 += v.y; ps2 += v.z; ps3 += v.w;
  }
  int g = tid >> 5, d0 = (tid & 31) * 4;
  red[g][d0] = ps0; red[g][d0 + 1] = ps1; red[g][d0 + 2] = ps2; red[g][d0 + 3] = ps3;
  __syncthreads();
  if (tid < 128){
    float s = 0.f;
    #pragma unroll
    for (int gg = 0; gg < 8; ++gg) s += red[gg][tid];
    meanJ[bi * 128 + tid] = s * (1.0f / N_);
  }
}

// ---- merged: y==0 attention (2 heads/wave, prefetch), y==1 meanI column pass ----
__global__ __launch_bounds__(256, 2) void kattnI(
    const unsigned short* __restrict__ E16, const unsigned short* __restrict__ WqkvT,
    const float* __restrict__ qkvn, float* __restrict__ attn,
    float* __restrict__ meanI){
  __shared__ float red[16][128];
  int tid = threadIdx.x;
  if (blockIdx.y == 1){
    // ---------------- meanI over i, vectorized 16B loads ----------------
    int bj = blockIdx.x; int b = bj / N_, j = bj % N_;
    int ig = tid >> 4, dsub = tid & 15;
    float acc[8];
    #pragma unroll
    for (int e = 0; e < 8; ++e) acc[e] = 0.f;
    #pragma unroll 4
    for (int i = ig; i < N_; i += 16){
      const unsigned short* p = E16 + ((size_t)(b * N_ + i) * N_ + j) * D_ + dsub * 8;
      uint4 u = *(const uint4*)p;
      acc[0] += bf2f((unsigned short)(u.x & 0xffff)); acc[1] += bf2f((unsigned short)(u.x >> 16));
      acc[2] += bf2f((unsigned short)(u.y & 0xffff)); acc[3] += bf2f((unsigned short)(u.y >> 16));
      acc[4] += bf2f((unsigned short)(u.z & 0xffff)); acc[5] += bf2f((unsigned short)(u.z >> 16));
      acc[6] += bf2f((unsigned short)(u.w & 0xffff)); acc[7] += bf2f((unsigned short)(u.w >> 16));
    }
    #pragma unroll
    for (int e = 0; e < 8; ++e) red[ig][dsub * 8 + e] = acc[e];
    __syncthreads();
    if (tid < 128){
      float s = 0.f;
      #pragma unroll
      for (int gg = 0; gg < 16; ++gg) s += red[gg][tid];
      meanI[bj * 128 + tid] = s * (1.0f / N_);
    }
    return;
  }
  // ---------------- attention ----------------
  int bi = blockIdx.x; int b = bi / N_;
  int w = tid >> 6, lane = tid & 63, quad = lane >> 4, c16 = lane & 15;
  const float scale = 0.08838834764831845f;   // 1/sqrt(128)
  const unsigned short* Abase = E16 + (size_t)bi * N_ * D_;

  bh8 bf[2][4][4];
  #pragma unroll
  for (int s = 0; s < 2; ++s){
    int h = w + s * 4;
    #pragma unroll
    for (int u = 0; u < 4; ++u)
      #pragma unroll
      for (int ks = 0; ks < 4; ++ks){
        int col = h * 64 + u * 16 + c16;
        bf[s][u][ks] = *(const bh8*)(WqkvT + col * 128 + ks * 32 + quad * 8);
      }
  }
  float qv[2];
  #pragma unroll
  for (int s = 0; s < 2; ++s) qv[s] = qkvn[bi * 384 + (w + s * 4) * 48 + c16];

  float m_run[2] = {-1e30f, -1e30f}, l_run[2] = {0.f, 0.f}, o[2] = {0.f, 0.f};
  bh8 af[4];
  #pragma unroll
  for (int ks = 0; ks < 4; ++ks)
    af[ks] = *(const bh8*)(Abase + (size_t)c16 * D_ + ks * 32 + quad * 8);

  for (int jt = 0; jt < 24; ++jt){
    int jn = (jt + 1 < 24) ? jt + 1 : 0;
    bh8 afn[4];
    #pragma unroll
    for (int ks = 0; ks < 4; ++ks)
      afn[ks] = *(const bh8*)(Abase + (size_t)(jn * 16 + c16) * D_ + ks * 32 + quad * 8);
    float knv[2][4], vnv[2][4];
    const float* kvb = qkvn + ((size_t)b * N_ + jt * 16 + quad * 4) * 384;
    #pragma unroll
    for (int s = 0; s < 2; ++s)
      #pragma unroll
      for (int r = 0; r < 4; ++r){
        knv[s][r] = kvb[r * 384 + (w + s * 4) * 48 + 16 + c16];
        vnv[s][r] = kvb[r * 384 + (w + s * 4) * 48 + 32 + c16];
      }
    f32x4 EQ[2], EK[2], EV[2], EM[2];
    #pragma unroll
    for (int s = 0; s < 2; ++s){ EQ[s] = zero4(); EK[s] = zero4(); EV[s] = zero4(); EM[s] = zero4(); }
    #pragma unroll
    for (int ks = 0; ks < 4; ++ks)
      #pragma unroll
      for (int s = 0; s < 2; ++s){
        EQ[s] = mfma_bf16(af[ks], bf[s][0][ks], EQ[s]);
        EK[s] = mfma_bf16(af[ks], bf[s][1][ks], EK[s]);
        EV[s] = mfma_bf16(af[ks], bf[s][2][ks], EV[s]);
        EM[s] = mfma_bf16(af[ks], bf[s][3][ks], EM[s]);
      }
    #pragma unroll
    for (int s = 0; s < 2; ++s){
      float dots[4], vv[4];
      #pragma unroll
      for (int r = 0; r < 4; ++r){
        float t1 = (qv[s] + EQ[s][r]) * (knv[s][r] + EK[s][r]);
        dots[r] = red16_add(t1) * scale;               // DPP instead of 4 ds_swizzle
        vv[r] = vnv[s][r] * EM[s][r] + EV[s][r];
      }
      float tmax = fmaxf(fmaxf(dots[0], dots[1]), fmaxf(dots[2], dots[3]));
      tmax = fmaxf(tmax, __shfl_xor(tmax, 16));
      tmax = fmaxf(tmax, __shfl_xor(tmax, 32));
      float mnew = fmaxf(m_run[s], tmax);
      float al = __expf(m_run[s] - mnew);
      float p0 = __expf(dots[0] - mnew), p1 = __expf(dots[1] - mnew);
      float p2 = __expf(dots[2] - mnew), p3 = __expf(dots[3] - mnew);
      float lt = p0 + p1 + p2 + p3;
      lt += __shfl_xor(lt, 16); lt += __shfl_xor(lt, 32);
      l_run[s] = l_run[s] * al + lt;
      m_run[s] = mnew;
      o[s] = o[s] * al + p0 * vv[0] + p1 * vv[1] + p2 * vv[2] + p3 * vv[3];
    }
    #pragma unroll
    for (int ks = 0; ks < 4; ++ks) af[ks] = afn[ks];
  }
  #pragma unroll
  for (int s = 0; s < 2; ++s){
    float oo = o[s];
    oo += __shfl_xor(oo, 16); oo += __shfl_xor(oo, 32);
    oo /= l_run[s];
    if (quad == 0) attn[(size_t)bi * D_ + (w + s * 4) * 16 + c16] = oo;
  }
}

// -------- merged node path: lin0+LN0+MLP+LN1 then rowAdd/colAdd GEMVs --------
__global__ void knodeadd(const float* __restrict__ node, const float* __restrict__ attn,
                         const float* lin0_w, const float* lin0_b,
                         const float* g0, const float* bb0,
                         const float* w1, const float* w2, const float* b2,
                         const float* g1, const float* bb1,
                         const float* __restrict__ meanJ, const float* __restrict__ meanI,
                         const float* ws, const float* bs, const float* wt, const float* bt,
                         const float* wer, const float* wec, const float* be,
                         float* __restrict__ xOut,
                         float* __restrict__ rowAdd, float* __restrict__ colAdd){
  int row = blockIdx.x; int tid = threadIdx.x;
  __shared__ float sa[128], sx[128], sh[256], rb[8], sx2[128], smJ[128], smI[128];
  if (tid < 128){
    sa[tid] = attn[row * 128 + tid];
    smJ[tid] = meanJ[row * 128 + tid];
    smI[tid] = meanI[row * 128 + tid];
  }
  __syncthreads();
  float y = 0.f, x0 = 0.f;
  if (tid < 128){
    float acc = lin0_b[tid];
    #pragma unroll 8
    for (int k = 0; k < 128; ++k) acc += sa[k] * lin0_w[k * 128 + tid];
    y = acc + node[row * 128 + tid];
  }
  { float sv = (tid < 128) ? y : 0.f, sq = (tid < 128) ? y * y : 0.f;
    sv = red16_add(sv); sq = red16_add(sq);
    sv += __shfl_xor(sv, 16); sq += __shfl_xor(sq, 16);
    sv += __shfl_xor(sv, 32); sq += __shfl_xor(sq, 32);
    if ((tid & 63) == 0){ rb[tid >> 6] = sv; rb[4 + (tid >> 6)] = sq; } }
  __syncthreads();
  float mean = (rb[0] + rb[1] + rb[2] + rb[3]) * (1.f / 128.f);
  float var  = (rb[4] + rb[5] + rb[6] + rb[7]) * (1.f / 128.f) - mean * mean;
  float rstd = rsqrtf(var + 1e-5f);
  if (tid < 128){ x0 = (y - mean) * rstd * g0[tid] + bb0[tid]; sx[tid] = x0; }
  __syncthreads();
  { float acc = 0.f;
    #pragma unroll 8
    for (int k = 0; k < 128; ++k) acc += sx[k] * w1[k * 256 + tid];
    sh[tid] = geluf(acc); }
  __syncthreads();
  float y2 = 0.f;
  if (tid < 128){
    float acc = b2[tid];
    #pragma unroll 8
    for (int e = 0; e < 256; ++e) acc += sh[e] * w2[e * 128 + tid];
    y2 = acc + x0;
  }
  __syncthreads();
  { float sv = (tid < 128) ? y2 : 0.f, sq = (tid < 128) ? y2 * y2 : 0.f;
    sv = red16_add(sv); sq = red16_add(sq);
    sv += __shfl_xor(sv, 16); sq += __shfl_xor(sq, 16);
    sv += __shfl_xor(sv, 32); sq += __shfl_xor(sq, 32);
    if ((tid & 63) == 0){ rb[tid >> 6] = sv; rb[4 + (tid >> 6)] = sq; } }
  __syncthreads();
  mean = (rb[0] + rb[1] + rb[2] + rb[3]) * (1.f / 128.f);
  var  = (rb[4] + rb[5] + rb[6] + rb[7]) * (1.f / 128.f) - mean * mean;
  rstd = rsqrtf(var + 1e-5f);
  if (tid < 128){
    float xv = (y2 - mean) * rstd * g1[tid] + bb1[tid];
    xOut[row * 128 + tid] = xv;
    sx2[tid] = xv;
  }
  __syncthreads();
  // ---- addends: tid<128 -> rowAdd (ws, wer); tid>=128 -> colAdd (wt, wec) ----
  if (tid < 128){
    int d = tid;
    float s1 = bs[d], s3 = 0.f;
    #pragma unroll 8
    for (int k = 0; k < 128; ++k){
      s1 += sx2[k] * ws[k * 128 + d];
      s3 += smJ[k] * wer[k * 128 + d];
    }
    rowAdd[row * 128 + d] = s1 + s3 + be[d];
  } else {
    int d = tid - 128;
    float s2 = bt[d], s4 = 0.f;
    #pragma unroll 8
    for (int k = 0; k < 128; ++k){
      s2 += sx2[k] * wt[k * 128 + d];
      s4 += smI[k] * wec[k * 128 + d];
    }
    colAdd[row * 128 + d] = s2 + s4;
  }
}

// -- fused edge pipeline v6: v4 structure (256 thr, 2 cols/wave) +
//    XOR chunk swizzle on sA/sT (kills 8-way ds_read_b128 conflicts) +
//    DPP-based LN reductions (moves ~2K ds_swizzle/block to VALU pipe).
//    LDS = 32768 + 16384 + 2048 + 512 = 51712 B -> 3 blocks/CU.
__global__ __launch_bounds__(256, 3) void kedge4(
    const unsigned short* __restrict__ E16, const unsigned short* __restrict__ WeT,
    const unsigned short* __restrict__ W1T, const unsigned short* __restrict__ E1W1T,
    const unsigned short* __restrict__ E1W2T,
    const float* __restrict__ rowAdd, const float* __restrict__ colAdd,
    const float* __restrict__ b1, const float* __restrict__ eg0, const float* __restrict__ eb0,
    const float* __restrict__ e1b2, const float* __restrict__ eg1, const float* __restrict__ eb1,
    float* __restrict__ eOut){
  __shared__ unsigned short sA[64][256];   // swizzled storage: (m,c) at col swz(m,c)
  __shared__ unsigned short sT[64][128];   // swizzled stage buffer
  __shared__ float lrS[4][64], lrQ[4][64];
  __shared__ float2 stats[64];             // per-row (mean, rstd)
  int tid = threadIdx.x;
  int w = tid >> 6, lane = tid & 63, quad = lane >> 4, c16 = lane & 15;
  int R0 = blockIdx.x * 64;
  int b = R0 / NN; int rem = R0 % NN; int i = rem / N_; int j0 = rem % N_;

  // ---- prefetch G1 weights + epilogue addends ----
  bh8 wb1[2][8];
  #pragma unroll
  for (int t = 0; t < 2; ++t)
    #pragma unroll
    for (int ks = 0; ks < 8; ++ks){
      int col = w * 32 + t * 16 + c16;
      wb1[t][ks] = *(const bh8*)(WeT + (size_t)col * 256 + ks * 32 + quad * 8);
    }
  float ca[2][16], rAv[2];
  #pragma unroll
  for (int t = 0; t < 2; ++t){
    rAv[t] = rowAdd[(b * N_ + i) * D_ + w * 32 + t * 16 + c16];
    #pragma unroll
    for (int ms = 0; ms < 4; ++ms)
      #pragma unroll
      for (int r = 0; r < 4; ++r)
        ca[t][ms * 4 + r] = colAdd[(size_t)(b * N_ + j0 + ms * 16 + quad * 4 + r) * D_
                                   + w * 32 + t * 16 + c16];
  }

  // ---- stage A = [edge(b,i,j0+m,:) | edge(b,j0+m,i,:)] bf16, 64x256, swizzled ----
  #pragma unroll
  for (int it = 0; it < 8; ++it){
    int cid = it * 256 + tid;
    int rrow = cid >> 5;
    int chunk = cid & 31;
    int kc = chunk * 8;
    const unsigned short* sp;
    if (kc < 128) sp = E16 + ((size_t)(b * N_ + i) * N_ + (j0 + rrow)) * D_ + kc;
    else          sp = E16 + ((size_t)(b * N_ + j0 + rrow) * N_ + i) * D_ + (kc - 128);
    *(float4*)&sA[rrow][(chunk ^ (rrow & 7)) << 3] = *(const float4*)sp;
  }
  __syncthreads();

  // ---- G1: A(64x256) @ WeT^T -> cols [32w,32w+32); +rowAdd+colAdd, gelu -> sT ----
  f32x4 acc1[2][4];
  #pragma unroll
  for (int t = 0; t < 2; ++t) for (int ms = 0; ms < 4; ++ms) acc1[t][ms] = zero4();
  #pragma unroll
  for (int ks = 0; ks < 8; ++ks){
    bh8 af[4];
    #pragma unroll
    for (int ms = 0; ms < 4; ++ms)
      af[ms] = *(const bh8*)&sA[ms * 16 + c16][((ks * 4 + quad) ^ (c16 & 7)) << 3];
    #pragma unroll
    for (int t = 0; t < 2; ++t)
      #pragma unroll
      for (int ms = 0; ms < 4; ++ms)
        acc1[t][ms] = mfma_bf16(af[ms], wb1[t][ks], acc1[t][ms]);
  }
  #pragma unroll
  for (int ms = 0; ms < 4; ++ms)
    #pragma unroll
    for (int r = 0; r < 4; ++r){
      int m = ms * 16 + quad * 4 + r;
      float v0 = gelu_fast(acc1[0][ms][r] + rAv[0] + ca[0][ms * 4 + r]);
      float v1 = gelu_fast(acc1[1][ms][r] + rAv[1] + ca[1][ms * 4 + r]);
      unsigned pk = f2bf_pk(v0, v1);
      sT[m][swz(m, w * 32 + c16)]      = (unsigned short)(pk & 0xffff);
      sT[m][swz(m, w * 32 + 16 + c16)] = (unsigned short)(pk >> 16);
    }
  __syncthreads();

  // ---- G2: gelu1 @ W1T^T + b1 + edge(bf16, sA) -> LN0 partials (DPP) ----
  bh8 wb2[2][4];
  #pragma unroll
  for (int t = 0; t < 2; ++t)
    #pragma unroll
    for (int ks = 0; ks < 4; ++ks){
      int col = w * 32 + t * 16 + c16;
      wb2[t][ks] = *(const bh8*)(W1T + (size_t)col * 128 + ks * 32 + quad * 8);
    }
  f32x4 acc2[2][4];
  #pragma unroll
  for (int t = 0; t < 2; ++t) for (int ms = 0; ms < 4; ++ms) acc2[t][ms] = zero4();
  #pragma unroll
  for (int ks = 0; ks < 4; ++ks){
    bh8 af[4];
    #pragma unroll
    for (int ms = 0; ms < 4; ++ms)
      af[ms] = *(const bh8*)&sT[ms * 16 + c16][((ks * 4 + quad) ^ (c16 & 7)) << 3];
    #pragma unroll
    for (int t = 0; t < 2; ++t)
      #pragma unroll
      for (int ms = 0; ms < 4; ++ms)
        acc2[t][ms] = mfma_bf16(af[ms], wb2[t][ks], acc2[t][ms]);
  }
  float b1v[2], g0v[2], b0v[2];
  #pragma unroll
  for (int t = 0; t < 2; ++t){
    int c = w * 32 + t * 16 + c16;
    b1v[t] = b1[c]; g0v[t] = eg0[c]; b0v[t] = eb0[c];
  }
  #pragma unroll
  for (int ms = 0; ms < 4; ++ms)
    #pragma unroll
    for (int r = 0; r < 4; ++r){
      int m = ms * 16 + quad * 4 + r;
      float s = 0.f, q = 0.f;
      #pragma unroll
      for (int t = 0; t < 2; ++t){
        float v = acc2[t][ms][r] + b1v[t] + bf2f(sA[m][swz(m, w * 32 + t * 16 + c16)]);
        acc2[t][ms][r] = v; s += v; q += v * v;
      }
      s = red16_add(s); q = red16_add(q);
      if (c16 == 0){ lrS[w][m] = s; lrQ[w][m] = q; }
    }
  __syncthreads();
  // ---- stats: wave w reduces rows [16w,16w+16) across the 4 wave-partials ----
  {
    int src = lane & 3, mrow = w * 16 + (lane >> 2);
    float sp = lrS[src][mrow], qp = lrQ[src][mrow];
    sp = red4_add(sp); qp = red4_add(qp);
    if (src == 0){
      float mean = sp * (1.f / 128.f);
      float var  = qp * (1.f / 128.f) - mean * mean;
      stats[mrow] = make_float2(mean, rsqrtf(var + 1e-5f));
    }
  }
  __syncthreads();
  // ---- LN0 finalize -> edge2 bf16 into sA cols 0..127 ----
  #pragma unroll
  for (int ms = 0; ms < 4; ++ms)
    #pragma unroll
    for (int r = 0; r < 4; ++r){
      int m = ms * 16 + quad * 4 + r;
      float2 st = stats[m];
      float e0 = (acc2[0][ms][r] - st.x) * st.y * g0v[0] + b0v[0];
      float e1 = (acc2[1][ms][r] - st.x) * st.y * g0v[1] + b0v[1];
      unsigned pk = f2bf_pk(e0, e1);
      sA[m][swz(m, w * 32 + c16)]      = (unsigned short)(pk & 0xffff);
      sA[m][swz(m, w * 32 + 16 + c16)] = (unsigned short)(pk >> 16);
    }
  __syncthreads();

  // ---- G3/G4 two-phase over K=256 ----
  f32x4 acc4[2][4];
  #pragma unroll
  for (int t = 0; t < 2; ++t) for (int ms = 0; ms < 4; ++ms) acc4[t][ms] = zero4();
  #pragma unroll
  for (int p = 0; p < 2; ++p){
    bh8 wb3[2][4];
    #pragma unroll
    for (int t = 0; t < 2; ++t)
      #pragma unroll
      for (int ks = 0; ks < 4; ++ks){
        int col = p * 128 + w * 32 + t * 16 + c16;
        wb3[t][ks] = *(const bh8*)(E1W1T + (size_t)col * 128 + ks * 32 + quad * 8);
      }
    f32x4 acc3[2][4];
    #pragma unroll
    for (int t = 0; t < 2; ++t) for (int ms = 0; ms < 4; ++ms) acc3[t][ms] = zero4();
    #pragma unroll
    for (int ks = 0; ks < 4; ++ks){
      bh8 af[4];
      #pragma unroll
      for (int ms = 0; ms < 4; ++ms)
        af[ms] = *(const bh8*)&sA[ms * 16 + c16][((ks * 4 + quad) ^ (c16 & 7)) << 3];
      #pragma unroll
      for (int t = 0; t < 2; ++t)
        #pragma unroll
        for (int ms = 0; ms < 4; ++ms)
          acc3[t][ms] = mfma_bf16(af[ms], wb3[t][ks], acc3[t][ms]);
    }
    #pragma unroll
    for (int ms = 0; ms < 4; ++ms)
      #pragma unroll
      for (int r = 0; r < 4; ++r){
        int m = ms * 16 + quad * 4 + r;
        float v0 = gelu_fast(acc3[0][ms][r]);
        float v1 = gelu_fast(acc3[1][ms][r]);
        unsigned pk = f2bf_pk(v0, v1);
        sT[m][swz(m, w * 32 + c16)]      = (unsigned short)(pk & 0xffff);
        sT[m][swz(m, w * 32 + 16 + c16)] = (unsigned short)(pk >> 16);
      }
    __syncthreads();
    bh8 wb4[2][4];
    #pragma unroll
    for (int t = 0; t < 2; ++t)
      #pragma unroll
      for (int k2 = 0; k2 < 4; ++k2){
        int col = w * 32 + t * 16 + c16;
        wb4[t][k2] = *(const bh8*)(E1W2T + (size_t)col * 256 + p * 128 + k2 * 32 + quad * 8);
      }
    #pragma unroll
    for (int k2 = 0; k2 < 4; ++k2){
      bh8 af[4];
      #pragma unroll
      for (int ms = 0; ms < 4; ++ms)
        af[ms] = *(const bh8*)&sT[ms * 16 + c16][((k2 * 4 + quad) ^ (c16 & 7)) << 3];
      #pragma unroll
      for (int t = 0; t < 2; ++t)
        #pragma unroll
        for (int ms = 0; ms < 4; ++ms)
          acc4[t][ms] = mfma_bf16(af[ms], wb4[t][k2], acc4[t][ms]);
    }
    __syncthreads();
  }

  // ---- G4 epilogue: + b2 + edge2(bf16, sA) -> LN1 (DPP) -> store ----
  float b2v[2], g1v[2], bb1v[2];
  #pragma unroll
  for (int t = 0; t < 2; ++t){
    int c = w * 32 + t * 16 + c16;
    b2v[t] = e1b2[c]; g1v[t] = eg1[c]; bb1v[t] = eb1[c];
  }
  #pragma unroll
  for (int ms = 0; ms < 4; ++ms)
    #pragma unroll
    for (int r = 0; r < 4; ++r){
      int m = ms * 16 + quad * 4 + r;
      float s = 0.f, q = 0.f;
      #pragma unroll
      for (int t = 0; t < 2; ++t){
        float v = acc4[t][ms][r] + b2v[t] + bf2f(sA[m][swz(m, w * 32 + t * 16 + c16)]);
        acc4[t][ms][r] = v; s += v; q += v * v;
      }
      s = red16_add(s); q = red16_add(q);
      if (c16 == 0){ lrS[w][m] = s; lrQ[w][m] = q; }
    }
  __syncthreads();
  {
    int src = lane & 3, mrow = w * 16 + (lane >> 2);
    float sp = lrS[src][mrow], qp = lrQ[src][mrow];
    sp = red4_add(sp); qp = red4_add(qp);
    if (src == 0){
      float mean = sp * (1.f / 128.f);
      float var  = qp * (1.f / 128.f) - mean * mean;
      stats[mrow] = make_float2(mean, rsqrtf(var + 1e-5f));
    }
  }
  __syncthreads();
  float* outBase = eOut + ((size_t)(b * N_ + i) * N_ + j0) * D_;
  #pragma unroll
  for (int ms = 0; ms < 4; ++ms)
    #pragma unroll
    for (int r = 0; r < 4; ++r){
      int m = ms * 16 + quad * 4 + r;
      float2 st = stats[m];
      #pragma unroll
      for (int t = 0; t < 2; ++t){
        int c = w * 32 + t * 16 + c16;
        outBase[(size_t)m * D_ + c] = (acc4[t][ms][r] - st.x) * st.y * g1v[t] + bb1v[t];
      }
    }
}

extern "C" void kernel_launch(void* const* d_in, const int* in_sizes, int n_in,
                              void* d_out, int out_size, void* d_ws, size_t ws_size,
                              hipStream_t stream){
  const float* node   = (const float*)d_in[0];
  const float* edge   = (const float*)d_in[1];
  const float* wqkv_n = (const float*)d_in[3];
  const float* wqkv_e = (const float*)d_in[4];
  const float* lin0_w = (const float*)d_in[5];
  const float* lin0_b = (const float*)d_in[6];
  const float* ln0_g  = (const float*)d_in[7];
  const float* ln0_b  = (const float*)d_in[8];
  const float* ln1_g  = (const float*)d_in[9];
  const float* ln1_b  = (const float*)d_in[10];
  const float* nmlp_w1= (const float*)d_in[11];
  const float* nmlp_w2= (const float*)d_in[12];
  const float* nmlp_b2= (const float*)d_in[13];
  const float* e0_we  = (const float*)d_in[14];
  const float* e0_be  = (const float*)d_in[15];
  const float* e0_ws  = (const float*)d_in[16];
  const float* e0_bs  = (const float*)d_in[17];
  const float* e0_wt  = (const float*)d_in[18];
  const float* e0_bt  = (const float*)d_in[19];
  const float* e0_wer = (const float*)d_in[20];
  const float* e0_wec = (const float*)d_in[21];
  const float* e0_w1  = (const float*)d_in[22];
  const float* e0_b1  = (const float*)d_in[23];
  const float* e1_w1  = (const float*)d_in[24];
  const float* e1_w2  = (const float*)d_in[25];
  const float* e1_b2  = (const float*)d_in[26];
  const float* eln0_g = (const float*)d_in[27];
  const float* eln0_b = (const float*)d_in[28];
  const float* eln1_g = (const float*)d_in[29];
  const float* eln1_b = (const float*)d_in[30];

  unsigned short* E16   = (unsigned short*)d_ws;
  unsigned short* WqkvT = E16 + (size_t)EDGE_ELEMS;
  unsigned short* WeT   = WqkvT + 65536;
  unsigned short* W1T   = WeT + 32768;
  unsigned short* E1W1T = W1T + 16384;
  unsigned short* E1W2T = E1W1T + 32768;
  float* fbase  = (float*)(E1W2T + 32768);
  float* qkvn   = fbase;
  float* attn   = qkvn + (size_t)BN * 384;
  float* meanJ  = attn + NODE_ELEMS;
  float* meanI  = meanJ + NODE_ELEMS;
  float* rowAdd = meanI + NODE_ELEMS;
  float* colAdd = rowAdd + NODE_ELEMS;

  float* xOut = (float*)d_out;
  float* eOut = xOut + NODE_ELEMS;

  kprep<<<dim3(BN, 6), 384, 0, stream>>>(wqkv_e, e0_we, e0_w1, e1_w1, e1_w2,
                                         node, wqkv_n,
                                         WqkvT, WeT, W1T, E1W1T, E1W2T, qkvn);
  kprepA<<<BN, 256, 0, stream>>>(edge, E16, meanJ);
  kattnI<<<dim3(BN, 2), 256, 0, stream>>>(E16, WqkvT, qkvn, attn, meanI);
  knodeadd<<<BN, 256, 0, stream>>>(node, attn, lin0_w, lin0_b, ln0_g, ln0_b,
                                   nmlp_w1, nmlp_w2, nmlp_b2, ln1_g, ln1_b,
                                   meanJ, meanI, e0_ws, e0_bs, e0_wt, e0_bt,
                                   e0_wer, e0_wec, e0_be,
                                   xOut, rowAdd, colAdd);
  kedge4<<<NN * B_ / 64, 256, 0, stream>>>(E16, WeT, W1T, E1W1T, E1W2T,
                                           rowAdd, colAdd, e0_b1,
                                           eln0_g, eln0_b, e1_b2, eln1_g, eln1_b,
                                           eOut);
}